// Round 7
// baseline (10637.515 us; speedup 1.0000x reference)
//
#include <hip/hip_runtime.h>
#include <stdint.h>
#include <math.h>

#define NPTS  8192
#define NB    2
#define NC    64
#define MCENT 2048
#define HH    128
#define K2NN  32
#define S1STR 132
#define GRID  98          // 2 FPS blocks + 96 consumers
#define SENT  0xFFFFFFFFu

// float offsets inside d_out (outputs concatenated flat, all read as fp32)
#define OUT0_OFF 0                                   // dsamp_xyz (B,M,3)
#define OUT1_OFF (NB*MCENT*3)                        // shifted   (B,2M,3)
#define OUT2_OFF (OUT1_OFF + NB*2*MCENT*3)           // feats     (B,2*O,M)
#define OUT3_OFF (OUT2_OFF + NB*2*HH*MCENT)          // idx       (B,M) as float

// LDS union layout (bytes). FPS role: xs/ys/zs mirror + warr.
// Consumer role: d2u (KNN) later overlapped by s1/s2 (EGNN), barrier-separated.
#define SM_SIZE  98432
#define SM_XS    0
#define SM_YS    32768
#define SM_ZS    65536
#define SM_FWARR 98304
#define SM_D2U   0
#define SM_S1    0
#define SM_S2    16896
#define SM_HJ    33792
#define SM_HI    41984
#define SM_REL   42240
#define SM_D2S   42624
#define SM_AGG   42752
#define SM_T1    43264
#define SM_COEF  43776
#define SM_NIDX  43904
#define SM_CWARR 44032
#define SM_PBC   44160

__device__ __forceinline__ float silu_f(float v){ return v / (1.0f + expf(-v)); }

// ---- fast wave-wide u32 butterfly reduce: 4x DPP + swizzle(xor16) + shfl(xor32)
template<int CTRL>
__device__ __forceinline__ unsigned dppmov(unsigned v){
  return (unsigned)__builtin_amdgcn_update_dpp(0, (int)v, CTRL, 0xF, 0xF, true);
}
__device__ __forceinline__ unsigned wave_max_u32(unsigned v){
  unsigned s;
  s = dppmov<0xB1>(v);  v = v > s ? v : s;   // xor1
  s = dppmov<0x4E>(v);  v = v > s ? v : s;   // xor2
  s = dppmov<0x141>(v); v = v > s ? v : s;   // half-row mirror
  s = dppmov<0x140>(v); v = v > s ? v : s;   // row mirror
  s = (unsigned)__builtin_amdgcn_ds_swizzle((int)v, 0x401F); v = v > s ? v : s; // xor16
  s = (unsigned)__shfl_xor((int)v, 32); v = v > s ? v : s;                      // xor32
  return v;
}
__device__ __forceinline__ unsigned wave_min_u32(unsigned v){
  unsigned s;
  s = dppmov<0xB1>(v);  v = v < s ? v : s;
  s = dppmov<0x4E>(v);  v = v < s ? v : s;
  s = dppmov<0x141>(v); v = v < s ? v : s;
  s = dppmov<0x140>(v); v = v < s ? v : s;
  s = (unsigned)__builtin_amdgcn_ds_swizzle((int)v, 0x401F); v = v < s ? v : s;
  s = (unsigned)__shfl_xor((int)v, 32); v = v < s ? v : s;
  return v;
}

// ---------------------------------------------------------------------------
// FPS (blocks 0..1). Raw s_barrier + lgkmcnt-only wait in the hot loop: the
// per-iteration agent-relaxed publish store stays outstanding (fire-and-forget)
// instead of being drained by __syncthreads' vmcnt(0).
// Exact reference semantics: contract off, numpy op order, first-max index.
// ---------------------------------------------------------------------------
__device__ void fps_block(const int b, const int tid,
                          const float* __restrict__ xyz,
                          unsigned* __restrict__ pa,
                          char* smem)
{
#pragma clang fp contract(off)
  float* xs = (float*)(smem + SM_XS);
  float* ys = (float*)(smem + SM_YS);
  float* zs = (float*)(smem + SM_ZS);
  unsigned long long (*warr)[8] = (unsigned long long (*)[8])(smem + SM_FWARR);
  const float* P = xyz + (size_t)b * NPTS * 3;

  float x[16], y[16], z[16], mind[16];
  #pragma unroll
  for (int j = 0; j < 16; ++j){
    const int p = tid*16 + j;
    const float px = P[p*3+0], py = P[p*3+1], pz = P[p*3+2];
    x[j]=px; y[j]=py; z[j]=pz; mind[j]=1e10f;
    xs[p]=px; ys[p]=py; zs[p]=pz;
  }
  float cx = P[0], cy = P[1], cz = P[2];
  if (tid == 0)
    __hip_atomic_store(&pa[b*MCENT], 0u, __ATOMIC_RELAXED, __HIP_MEMORY_SCOPE_AGENT);
  __syncthreads();

  for (int t = 1; t < MCENT; ++t){
    float bestv = -1.0f; int bestp = tid*16;
    #pragma unroll
    for (int j = 0; j < 16; ++j){
      const float dx = x[j]-cx, dy = y[j]-cy, dz = z[j]-cz;
      const float d  = (dx*dx + dy*dy) + dz*dz;   // contract off: per-op rounding
      const float mn = fminf(mind[j], d);
      mind[j] = mn;
      if (mn > bestv){ bestv = mn; bestp = tid*16 + j; }  // first-max kept
    }
    // wave-wide value max (bestv >= 0 so u32 order == f32 order), then the
    // lowest tied lane = lowest point index (blocked point assignment).
    const unsigned vb = __float_as_uint(bestv);
    const unsigned wv = wave_max_u32(vb);
    const unsigned long long bal = __ballot(vb == wv);
    const int lane = __ffsll(bal) - 1;
    const int wp   = __shfl(bestp, lane);
    if ((tid & 63) == 0)
      warr[t & 1][tid >> 6] = ((unsigned long long)wv << 32) | (unsigned)(NPTS-1-wp);
    // LDS-only barrier: order the warr write, do NOT drain the vm store queue.
    asm volatile("s_waitcnt lgkmcnt(0)" ::: "memory");
    __builtin_amdgcn_s_barrier();
    unsigned long long kb = warr[t & 1][0];
    #pragma unroll
    for (int w = 1; w < 8; ++w){
      const unsigned long long k2 = warr[t & 1][w];
      if (k2 > kb) kb = k2;                        // ties -> larger (N-1-p) = smaller p
    }
    const int p = NPTS - 1 - (int)(kb & 0xFFFFFFFFULL);
    cx = xs[p]; cy = ys[p]; cz = zs[p];
    if (tid == 0)
      __hip_atomic_store(&pa[b*MCENT + t], (unsigned)p,
                         __ATOMIC_RELAXED, __HIP_MEMORY_SCOPE_AGENT);
  }
}

// ---------------------------------------------------------------------------
// KNN (consumer phase 1): exact 32-NN ascending by (d2, idx), 512 threads,
// per-thread top-2 cache, double-buffered warr. Center xyz derived from the
// published index (no dependence on producer's non-atomic writes).
// ---------------------------------------------------------------------------
__device__ void knn512(const int b, const float cx, const float cy, const float cz,
                       const int tid, const float* __restrict__ xyz, char* smem)
{
#pragma clang fp contract(off)
  unsigned* d2u = (unsigned*)(smem + SM_D2U);
  unsigned long long (*warr)[8] = (unsigned long long (*)[8])(smem + SM_CWARR);
  int* nidx = (int*)(smem + SM_NIDX);
  const float* P = xyz + (size_t)b*NPTS*3;
  const float cn = (cx*cx + cy*cy) + cz*cz;

  unsigned long long best=~0ULL, second=~0ULL;
  #pragma unroll 4
  for (int j = 0; j < NPTS/512; ++j){
    const int p = tid + 512*j;
    const float px=P[p*3+0], py=P[p*3+1], pz=P[p*3+2];
    const float pn=(px*px+py*py)+pz*pz;
    const float e =(cx*px+cy*py)+cz*pz;
    const float d2=(cn+pn)-2.0f*e;                 // reference formula / op order
    unsigned u = __float_as_uint(d2);
    u = (u & 0x80000000u) ? ~u : (u | 0x80000000u);
    d2u[p] = u;
    const unsigned long long kk = ((unsigned long long)u<<32) | (unsigned)p;
    if (kk < best){ second = best; best = kk; }
    else if (kk < second){ second = kk; }
  }
  __syncthreads();

  for (int it = 0; it < K2NN; ++it){
    const unsigned vb = (unsigned)(best>>32);
    const unsigned wv = wave_min_u32(vb);
    const unsigned long long bal = __ballot(vb == wv);
    unsigned long long k;
    if (__popcll(bal) == 1){
      const int lane = __ffsll(bal)-1;
      const unsigned lp = (unsigned)__shfl((int)(unsigned)best, lane);  // low32 = p
      k = ((unsigned long long)wv<<32) | lp;
    } else {
      k = best;                                     // exact u64 fallback (rare tie)
      #pragma unroll
      for (int o = 32; o > 0; o >>= 1){
        const unsigned long long k2 = __shfl_xor(k, o);
        if (k2 < k) k = k2;
      }
    }
    if ((tid & 63) == 0) warr[it & 1][tid >> 6] = k;
    __syncthreads();
    unsigned long long kb = warr[it & 1][tid & 7];
    #pragma unroll
    for (int o = 4; o > 0; o >>= 1){
      const unsigned long long k2 = __shfl_xor(kb, o);
      if (k2 < kb) kb = k2;                        // u64 min: ties pick min p
    }
    const unsigned p = (unsigned)kb;
    if (tid == 0) nidx[it] = (int)p;
    if (best == kb){                               // unique owner (keys unique by p)
      d2u[p] = 0xFFFFFFFFu;
      best = second; second = ~0ULL;
      if (best == ~0ULL){                          // top-2 exhausted: rescan own part
        #pragma unroll 4
        for (int j = 0; j < NPTS/512; ++j){
          const int q = tid + 512*j;
          const unsigned long long kk = ((unsigned long long)d2u[q]<<32)|(unsigned)q;
          if (kk < best){ second = best; best = kk; }
          else if (kk < second){ second = kk; }
        }
      }
    }
  }
  __syncthreads();   // nidx visible to staging
}

// ---------------------------------------------------------------------------
// EGNN per-scale (consumer phase 2), 512 threads: h = tid&127, 4 j-groups.
// ---------------------------------------------------------------------------
template<int KNB>
__device__ void egnn_scale512(const int isc, const int b, const int m, const int tid,
    const float* __restrict__ we1, const float* __restrict__ be1,
    const float* __restrict__ we2, const float* __restrict__ be2,
    const float* __restrict__ wxw, const float* __restrict__ bxw,
    const float* __restrict__ wh1, const float* __restrict__ bh1,
    const float* __restrict__ wh2, const float* __restrict__ bh2,
    const float* hi, const float (*hj)[NC], const float (*rel)[3], const float* d2s,
    float (*s1)[S1STR], float (*s2)[S1STR], float* coefs, float* aggs, float* t1,
    const float cx, const float cy, const float cz, float* __restrict__ out)
{
  constexpr int KH = KNB/4;
  const int h  = tid & 127;
  const int jg = tid >> 7;            // 0..3
  const int j0 = jg * KH;
  const float* W1 = we1 + (size_t)isc*(2*NC+1)*HH;
  const float* W2 = we2 + (size_t)isc*HH*HH;

  // ---- edge layer 1: [h_i, h_j, d2] @ we1 + be1, silu (h_i dot shared over j)
  float shi = be1[isc*HH + h];
  for (int r = 0; r < NC; ++r) shi += hi[r]*W1[r*HH + h];
  float acc[KH];
  #pragma unroll
  for (int jl = 0; jl < KH; ++jl) acc[jl] = shi;
  for (int r4 = 0; r4 < NC/4; ++r4){
    const float w0 = W1[(NC+4*r4+0)*HH+h];
    const float w1 = W1[(NC+4*r4+1)*HH+h];
    const float w2 = W1[(NC+4*r4+2)*HH+h];
    const float w3 = W1[(NC+4*r4+3)*HH+h];
    #pragma unroll
    for (int jl = 0; jl < KH; ++jl){
      const float4 v = *(const float4*)&hj[j0+jl][4*r4];
      acc[jl] += v.x*w0; acc[jl] += v.y*w1; acc[jl] += v.z*w2; acc[jl] += v.w*w3;
    }
  }
  {
    const float wd = W1[2*NC*HH + h];
    #pragma unroll
    for (int jl = 0; jl < KH; ++jl)
      s1[j0+jl][h] = silu_f(acc[jl] + d2s[j0+jl]*wd);
  }
  __syncthreads();

  // ---- edge layer 2
  float acc2[KH];
  { const float b2 = be2[isc*HH+h];
    #pragma unroll
    for (int jl=0;jl<KH;++jl) acc2[jl]=b2; }
  for (int r4 = 0; r4 < HH/4; ++r4){
    const float w0 = W2[(4*r4+0)*HH+h];
    const float w1 = W2[(4*r4+1)*HH+h];
    const float w2 = W2[(4*r4+2)*HH+h];
    const float w3 = W2[(4*r4+3)*HH+h];
    #pragma unroll
    for (int jl=0;jl<KH;++jl){
      const float4 v = *(const float4*)&s1[j0+jl][4*r4];
      acc2[jl]+=v.x*w0; acc2[jl]+=v.y*w1; acc2[jl]+=v.z*w2; acc2[jl]+=v.w*w3;
    }
  }
  #pragma unroll
  for (int jl=0;jl<KH;++jl) s2[j0+jl][h] = silu_f(acc2[jl]);
  __syncthreads();

  // ---- agg (tid<128) and coef per j (tid 128..128+KNB)
  if (tid < HH){
    float a = 0.f;
    #pragma unroll
    for (int j = 0; j < KNB; ++j) a += s2[j][tid];
    aggs[tid] = a;
  } else if (tid < HH + KNB){
    const int j = tid - HH;
    const float* WX = wxw + isc*HH;
    float c = 0.f;
    for (int r = 0; r < HH; ++r) c += s2[j][r]*WX[r];
    coefs[j] = c + bxw[isc];
  }
  __syncthreads();

  if (tid < 3){
    float s = 0.f;
    #pragma unroll
    for (int j = 0; j < KNB; ++j) s += rel[j][tid]*coefs[j];
    const float cc = (tid==0)?cx:((tid==1)?cy:cz);
    out[OUT1_OFF + ((size_t)(b*2+isc)*MCENT + m)*3 + tid] = cc + s*(1.0f/KNB);
  }
  if (tid < HH){
    const float* WH1 = wh1 + (size_t)isc*(NC+HH)*HH;
    float n = bh1[isc*HH + tid];
    for (int r = 0; r < NC; ++r) n += hi[r]*WH1[r*HH+tid];
    for (int r = 0; r < HH; ++r) n += aggs[r]*WH1[(NC+r)*HH+tid];
    t1[tid] = silu_f(n);
  }
  __syncthreads();
  if (tid < HH){
    const float* WH2 = wh2 + (size_t)isc*HH*HH;
    float v = bh2[isc*HH + tid];
    for (int r = 0; r < HH; ++r) v += t1[r]*WH2[r*HH+tid];
    out[OUT2_OFF + ((size_t)(b*2*HH) + isc*HH + tid)*MCENT + m] = v;
  }
  __syncthreads();   // before smem reuse by next scale / next item
}

// ---------------------------------------------------------------------------
// Consumer blocks 2..97: tid0-only low-rate poll of pa[item] (value IS the
// payload), LDS broadcast; then KNN + EGNN for the item.
// ---------------------------------------------------------------------------
__device__ void consumer_block(const int tid,
    const float* __restrict__ xyz, const float* __restrict__ feat,
    const float* __restrict__ we1, const float* __restrict__ be1,
    const float* __restrict__ we2, const float* __restrict__ be2,
    const float* __restrict__ wxw, const float* __restrict__ bxw,
    const float* __restrict__ wh1, const float* __restrict__ bh1,
    const float* __restrict__ wh2, const float* __restrict__ bh2,
    unsigned* __restrict__ pa, float* __restrict__ out, char* smem)
{
  float (*s1)[S1STR] = (float (*)[S1STR])(smem + SM_S1);
  float (*s2)[S1STR] = (float (*)[S1STR])(smem + SM_S2);
  float (*hj)[NC]    = (float (*)[NC])(smem + SM_HJ);
  float* hi    = (float*)(smem + SM_HI);
  float (*rel)[3] = (float (*)[3])(smem + SM_REL);
  float* d2s   = (float*)(smem + SM_D2S);
  float* aggs  = (float*)(smem + SM_AGG);
  float* t1    = (float*)(smem + SM_T1);
  float* coefs = (float*)(smem + SM_COEF);
  int* nidx    = (int*)(smem + SM_NIDX);
  int* pbc     = (int*)(smem + SM_PBC);

  const int nitems = NB*MCENT;
  for (int item = (int)blockIdx.x - NB; item < nitems; item += (int)gridDim.x - NB){
    const int b = item >> 11;
    const int m = item & (MCENT-1);
    if (tid == 0){
      unsigned pv = __hip_atomic_load(&pa[item], __ATOMIC_RELAXED, __HIP_MEMORY_SCOPE_AGENT);
      long spins = 0;
      while (pv == SENT){
        __builtin_amdgcn_s_sleep(64);    // ~4k cycles between polls
        pv = __hip_atomic_load(&pa[item], __ATOMIC_RELAXED, __HIP_MEMORY_SCOPE_AGENT);
        if (++spins > 2000000L) break;   // never expected; avoids infinite hang
      }
      pbc[0] = (pv >= NPTS) ? 0 : (int)pv;
    }
    __syncthreads();
    const int p = pbc[0];

    const float* P = xyz + (size_t)b*NPTS*3;
    const float cx = P[p*3+0], cy = P[p*3+1], cz = P[p*3+2];
    if (tid == 0) out[OUT3_OFF + item] = (float)p;
    if (tid < 3)  out[OUT0_OFF + (size_t)item*3 + tid] = P[p*3+tid];

    knn512(b, cx, cy, cz, tid, xyz, smem);

    if (tid < NC) hi[tid] = feat[((size_t)b*NC + tid)*NPTS + p];
    if (tid < K2NN){
      const int q = nidx[tid];
      const float rx = cx - P[q*3+0];
      const float ry = cy - P[q*3+1];
      const float rz = cz - P[q*3+2];
      rel[tid][0]=rx; rel[tid][1]=ry; rel[tid][2]=rz;
      d2s[tid] = rx*rx + ry*ry + rz*rz;
    }
    {
      const int j  = tid >> 4;             // 0..31
      const int c0 = (tid & 15) * 4;
      const int q  = nidx[j];
      #pragma unroll
      for (int w = 0; w < 4; ++w)
        hj[j][c0+w] = feat[((size_t)b*NC + c0 + w)*NPTS + q];
    }
    __syncthreads();

    egnn_scale512<16>(0, b, m, tid, we1,be1,we2,be2,wxw,bxw,wh1,bh1,wh2,bh2,
                      hi, hj, rel, d2s, s1, s2, coefs, aggs, t1, cx, cy, cz, out);
    egnn_scale512<32>(1, b, m, tid, we1,be1,we2,be2,wxw,bxw,wh1,bh1,wh2,bh2,
                      hi, hj, rel, d2s, s1, s2, coefs, aggs, t1, cx, cy, cz, out);
  }
}

// ---------------------------------------------------------------------------
__global__ __launch_bounds__(512, 2) void fused_kernel(
    const float* __restrict__ xyz, const float* __restrict__ feat,
    const float* __restrict__ we1, const float* __restrict__ be1,
    const float* __restrict__ we2, const float* __restrict__ be2,
    const float* __restrict__ wxw, const float* __restrict__ bxw,
    const float* __restrict__ wh1, const float* __restrict__ bh1,
    const float* __restrict__ wh2, const float* __restrict__ bh2,
    unsigned* __restrict__ pa, float* __restrict__ out)
{
  __shared__ __align__(16) char smem[SM_SIZE];
  const int tid = threadIdx.x;
  if (blockIdx.x < NB){
    fps_block((int)blockIdx.x, tid, xyz, pa, smem);
  } else {
    consumer_block(tid, xyz, feat, we1,be1,we2,be2,wxw,bxw,wh1,bh1,wh2,bh2,
                   pa, out, smem);
  }
}

__global__ void init_kernel(unsigned* __restrict__ pa){
  const int i = threadIdx.x + blockIdx.x * blockDim.x;
  if (i < NB*MCENT) pa[i] = SENT;
}

// ---------------------------------------------------------------------------
extern "C" void kernel_launch(void* const* d_in, const int* in_sizes, int n_in,
                              void* d_out, int out_size, void* d_ws, size_t ws_size,
                              hipStream_t stream){
  const float* xyz = (const float*)d_in[0];
  const float* feat= (const float*)d_in[1];
  const float* we1 = (const float*)d_in[2];
  const float* be1 = (const float*)d_in[3];
  const float* we2 = (const float*)d_in[4];
  const float* be2 = (const float*)d_in[5];
  const float* wxw = (const float*)d_in[6];
  const float* bxw = (const float*)d_in[7];
  const float* wh1 = (const float*)d_in[8];
  const float* bh1 = (const float*)d_in[9];
  const float* wh2 = (const float*)d_in[10];
  const float* bh2 = (const float*)d_in[11];
  float* out = (float*)d_out;

  unsigned* pa = (unsigned*)d_ws;        // NB*MCENT publish slots (16 KB)

  init_kernel <<<dim3(8),    dim3(512), 0, stream>>>(pa);
  fused_kernel<<<dim3(GRID), dim3(512), 0, stream>>>(xyz, feat,
      we1, be1, we2, be2, wxw, bxw, wh1, bh1, wh2, bh2, pa, out);
}

// Round 8
// 4303.571 us; speedup vs baseline: 2.4718x; 2.4718x over previous
//
#include <hip/hip_runtime.h>
#include <stdint.h>
#include <math.h>

#define NPTS  8192
#define NB    2
#define NC    64
#define MCENT 2048
#define HH    128
#define K2NN  32
#define NCELL 4096          // 16^3 spatial cells

typedef unsigned long long ull;

// float offsets inside d_out (outputs concatenated flat, all read as fp32)
#define OUT0_OFF 0                                   // dsamp_xyz (B,M,3)
#define OUT1_OFF (NB*MCENT*3)                        // shifted   (B,2M,3)
#define OUT2_OFF (OUT1_OFF + NB*2*MCENT*3)           // feats     (B,2*O,M)
#define OUT3_OFF (OUT2_OFF + NB*2*HH*MCENT)          // idx       (B,M) as float

// fps LDS layout (bytes). cnt/off (sort-time) share the mind region.
#define F_SX    0
#define F_SY    32768
#define F_SZ    65536
#define F_MIND  98304       // 32KB: mind[8192]; during sort cnt[4096]+off[4096]
#define F_CNT   98304
#define F_OFF   114688
#define F_SORIG 131072      // u16 x 8192
#define F_GK    147456      // u64 x 512
#define F_LIST  151552      // u16 x 512
#define F_WARR  152576      // u64 x 2 x 8
#define F_PART  152704      // int x 512 (sort scan)
#define F_NLIST 154752      // int
#define F_SIZE  154816      // ~151.2 KB (< 160 KiB)

__device__ __forceinline__ float silu_f(float v){ return v / (1.0f + expf(-v)); }

// ---- fast wave-wide u32 butterfly reduce: 4x DPP + swizzle(xor16) + shfl(xor32)
template<int CTRL>
__device__ __forceinline__ unsigned dppmov(unsigned v){
  return (unsigned)__builtin_amdgcn_update_dpp(0, (int)v, CTRL, 0xF, 0xF, true);
}
__device__ __forceinline__ unsigned wave_max_u32(unsigned v){
  unsigned s;
  s = dppmov<0xB1>(v);  v = v > s ? v : s;   // xor1
  s = dppmov<0x4E>(v);  v = v > s ? v : s;   // xor2
  s = dppmov<0x141>(v); v = v > s ? v : s;   // xor4 (half-row mirror)
  s = dppmov<0x140>(v); v = v > s ? v : s;   // xor8 (row mirror)
  s = (unsigned)__builtin_amdgcn_ds_swizzle((int)v, 0x401F); v = v > s ? v : s; // xor16
  s = (unsigned)__shfl_xor((int)v, 32); v = v > s ? v : s;                      // xor32
  return v;
}
__device__ __forceinline__ unsigned wave_min_u32(unsigned v){
  unsigned s;
  s = dppmov<0xB1>(v);  v = v < s ? v : s;
  s = dppmov<0x4E>(v);  v = v < s ? v : s;
  s = dppmov<0x141>(v); v = v < s ? v : s;
  s = dppmov<0x140>(v); v = v < s ? v : s;
  s = (unsigned)__builtin_amdgcn_ds_swizzle((int)v, 0x401F); v = v < s ? v : s;
  s = (unsigned)__shfl_xor((int)v, 32); v = v < s ? v : s;
  return v;
}

// LDS-only barrier: order LDS producer->consumer, don't drain global stores
// (fps main loop never reads back its global stores; kernel end drains them).
__device__ __forceinline__ void bar_lds(){
  asm volatile("s_waitcnt lgkmcnt(0)" ::: "memory");
  __builtin_amdgcn_s_barrier();
}

// ---------------------------------------------------------------------------
// Kernel 1: FPS with exact triangle-inequality pruning.
// Points counting-sorted into 16^3 cells (one-time). 512 groups x 16 sorted
// points; per group: center+radius (registers), mind in LDS, u64 key
// (valbits<<32)|((8191-orig)<<13)|sortpos in gk[]. Per iteration:
//   test -> compact touched groups -> rescan only those (reference op order)
//   -> block argmax over gk -> winner coords from sx[sortpos].
// Skip is EXACT: skip only if provably d2_ref(p,c) > mind_p for all p in the
// group (conservative margins ~1e-4 >> fp32 error). min(a,b)=a is exact.
// Tie-break: max key => max val, then min orig (orig unique => sortpos bits
// never decide). First-max semantics preserved exactly.
// ---------------------------------------------------------------------------
__global__ __launch_bounds__(512, 1) void fps_kernel(const float* __restrict__ xyz,
                                                     float* __restrict__ out,
                                                     int* __restrict__ ws_idx){
#pragma clang fp contract(off)
  __shared__ __align__(16) char smem[F_SIZE];
  float* sx   = (float*)(smem + F_SX);
  float* sy   = (float*)(smem + F_SY);
  float* sz   = (float*)(smem + F_SZ);
  float* mind = (float*)(smem + F_MIND);
  int*   cnt  = (int*)(smem + F_CNT);
  int*   off  = (int*)(smem + F_OFF);
  unsigned short* sorig = (unsigned short*)(smem + F_SORIG);
  ull*   gk   = (ull*)(smem + F_GK);
  unsigned short* list  = (unsigned short*)(smem + F_LIST);
  ull (*warr)[8] = (ull (*)[8])(smem + F_WARR);
  int*   part = (int*)(smem + F_PART);
  int*   nlist= (int*)(smem + F_NLIST);

  const int b   = blockIdx.x;
  const int tid = threadIdx.x;
  const int lane = tid & 63, wid = tid >> 6;
  const float* P = xyz + (size_t)b * NPTS * 3;

  // ---- load own 16 original points, compute cells, count
  float lx[16], ly[16], lz[16]; int lc[16];
  for (int i = tid; i < NCELL; i += 512) cnt[i] = 0;
  __syncthreads();
  #pragma unroll
  for (int j = 0; j < 16; ++j){
    const int p = tid*16 + j;
    const float x = P[p*3+0], y = P[p*3+1], z = P[p*3+2];
    lx[j]=x; ly[j]=y; lz[j]=z;
    int ix = (int)floorf((x + 5.0f) * 1.6f); ix = ix<0?0:(ix>15?15:ix);
    int iy = (int)floorf((y + 5.0f) * 1.6f); iy = iy<0?0:(iy>15?15:iy);
    int iz = (int)floorf((z + 5.0f) * 1.6f); iz = iz<0?0:(iz>15?15:iz);
    lc[j] = (ix<<8)|(iy<<4)|iz;
    atomicAdd(&cnt[lc[j]], 1);
  }
  __syncthreads();
  // ---- exclusive scan cnt -> off
  { int s = 0;
    #pragma unroll
    for (int k = 0; k < 8; ++k) s += cnt[tid*8+k];
    part[tid] = s; }
  __syncthreads();
  if (tid == 0){ int run = 0;
    for (int i = 0; i < 512; ++i){ const int v = part[i]; part[i] = run; run += v; } }
  __syncthreads();
  { int bse = part[tid];
    #pragma unroll
    for (int k = 0; k < 8; ++k){ off[tid*8+k] = bse; bse += cnt[tid*8+k]; } }
  __syncthreads();
  // ---- scatter into sorted order (order within cell nondeterministic; outputs
  // are permutation-invariant: keys carry orig, sortpos can't decide ties)
  #pragma unroll
  for (int j = 0; j < 16; ++j){
    const int pos = atomicAdd(&off[lc[j]], 1);
    sx[pos]=lx[j]; sy[pos]=ly[j]; sz[pos]=lz[j];
    sorig[pos] = (unsigned short)(tid*16 + j);
  }
  __syncthreads();
  // ---- group stats (group = sorted [tid*16, tid*16+16)) + init mind/gk
  float gcx=0.f, gcy=0.f, gcz=0.f;
  #pragma unroll
  for (int j = 0; j < 16; ++j){ gcx += sx[tid*16+j]; gcy += sy[tid*16+j]; gcz += sz[tid*16+j]; }
  gcx *= 0.0625f; gcy *= 0.0625f; gcz *= 0.0625f;
  float r2 = 0.f;
  #pragma unroll
  for (int j = 0; j < 16; ++j){
    const float dx = sx[tid*16+j]-gcx, dy = sy[tid*16+j]-gcy, dz = sz[tid*16+j]-gcz;
    r2 = fmaxf(r2, dx*dx + dy*dy + dz*dz);
  }
  const float gr = sqrtf(r2)*1.0005f + 1e-5f;   // inflated radius (conservative)
  for (int i = tid; i < NPTS; i += 512) mind[i] = 1e10f;   // overwrites cnt/off
  gk[tid] = ((ull)__float_as_uint(1e10f) << 32);           // never skippable vs 1e10
  float cx = P[0], cy = P[1], cz = P[2];
  if (tid == 0){
    *nlist = 0;
    ws_idx[b*MCENT] = 0;
    out[OUT3_OFF + b*MCENT] = 0.0f;
    out[OUT0_OFF + (size_t)(b*MCENT)*3 + 0] = cx;
    out[OUT0_OFF + (size_t)(b*MCENT)*3 + 1] = cy;
    out[OUT0_OFF + (size_t)(b*MCENT)*3 + 2] = cz;
  }
  __syncthreads();

  for (int t = 1; t < MCENT; ++t){
    // ---- test own group; compact touched groups into list
    const ull   myk  = gk[tid];
    const float gmax = __uint_as_float((unsigned)(myk >> 32));
    const float dxg = gcx-cx, dyg = gcy-cy, dzg = gcz-cz;
    const float dg  = dxg*dxg + dyg*dyg + dzg*dzg;
    const float lb  = sqrtf(dg)*0.99995f - gr;   // safe lower bound on dist(c, member)
    bool touched = true;
    if (lb > 0.0f) touched = !(lb*lb*0.9999f > gmax);
    const ull mask = __ballot(touched);
    int base0 = 0;
    if (lane == 0 && mask) base0 = atomicAdd(nlist, __popcll(mask));
    base0 = __shfl(base0, 0);
    if (touched){
      const int pfx = __popcll(mask & ((1ULL << lane) - 1ULL));
      list[base0 + pfx] = (unsigned short)tid;
    }
    bar_lds();                                   // bar1: list ready
    // ---- rescan touched groups (reference op order; min updates exact)
    const int n = *nlist;
    if (tid < n){
      const int g  = list[tid];
      const int sb = g << 4;
      ull bk = 0;
      for (int j = 0; j < 16; ++j){
        const int sp = sb + j;
        const float dx = sx[sp]-cx, dy = sy[sp]-cy, dz = sz[sp]-cz;
        const float d  = (dx*dx + dy*dy) + dz*dz;          // per-op rounded
        const float mn = fminf(mind[sp], d);
        mind[sp] = mn;
        const ull key = ((ull)__float_as_uint(mn) << 32)
                      | ((ull)(unsigned)(NPTS-1-(int)sorig[sp]) << 13)
                      | (unsigned)sp;
        if (key > bk) bk = key;
      }
      gk[g] = bk;
    }
    bar_lds();                                   // bar2: gk/mind updated
    // ---- block argmax over gk[512]: value-DPP fast path + exact u64 fallback
    const ull k2 = gk[tid];
    const unsigned vb = (unsigned)(k2 >> 32);
    const unsigned wm = wave_max_u32(vb);
    const ull balm = __ballot(vb == wm);
    ull wkey;
    if (__popcll(balm) == 1){
      const int sl = __ffsll(balm) - 1;
      wkey = __shfl(k2, sl);
    } else {
      wkey = k2;                                  // rare: exact u64 butterfly
      #pragma unroll
      for (int o = 32; o > 0; o >>= 1){
        const ull q = __shfl_xor(wkey, o);
        if (q > wkey) wkey = q;
      }
    }
    if (lane == 0) warr[t & 1][wid] = wkey;
    if (tid == 0) *nlist = 0;                     // reset for next iter (pre-bar3)
    bar_lds();                                   // bar3: warr ready
    ull best = warr[t & 1][0];
    #pragma unroll
    for (int w = 1; w < 8; ++w){ const ull q = warr[t & 1][w]; if (q > best) best = q; }
    const int sp    = (int)(best & 0x1FFFULL);
    const int porig = NPTS - 1 - (int)((best >> 13) & 0x1FFFULL);
    cx = sx[sp]; cy = sy[sp]; cz = sz[sp];        // uniform broadcast reads
    if (tid == 0){
      ws_idx[b*MCENT + t] = porig;
      out[OUT3_OFF + b*MCENT + t] = (float)porig;
      out[OUT0_OFF + (size_t)(b*MCENT + t)*3 + 0] = cx;
      out[OUT0_OFF + (size_t)(b*MCENT + t)*3 + 1] = cy;
      out[OUT0_OFF + (size_t)(b*MCENT + t)*3 + 2] = cz;
    }
  }
}

// ---------------------------------------------------------------------------
// Kernel 2: exact 32-NN per center (round-2 proven, unchanged).
// ---------------------------------------------------------------------------
__global__ __launch_bounds__(256) void knn_kernel(const float* __restrict__ xyz,
                                                  const float* __restrict__ out,
                                                  int* __restrict__ ws_knn){
#pragma clang fp contract(off)
  __shared__ unsigned d2u[NPTS];
  __shared__ unsigned long long warr[2][4];
  const int blk = blockIdx.x;
  const int b = blk / MCENT, m = blk % MCENT;
  const int tid = threadIdx.x;
  const float* P = xyz + (size_t)b*NPTS*3;
  const float cx = out[OUT0_OFF + (size_t)(b*MCENT+m)*3 + 0];
  const float cy = out[OUT0_OFF + (size_t)(b*MCENT+m)*3 + 1];
  const float cz = out[OUT0_OFF + (size_t)(b*MCENT+m)*3 + 2];
  const float cn = (cx*cx + cy*cy) + cz*cz;

  unsigned long long best = ~0ULL, second = ~0ULL;
  #pragma unroll 4
  for (int j = 0; j < NPTS/256; ++j){
    const int p = tid + 256*j;
    const float px = P[p*3+0], py = P[p*3+1], pz = P[p*3+2];
    const float pn = (px*px + py*py) + pz*pz;
    const float e  = (cx*px + cy*py) + cz*pz;
    const float d2 = (cn + pn) - 2.0f*e;           // reference formula / op order
    unsigned u = __float_as_uint(d2);
    u = (u & 0x80000000u) ? ~u : (u | 0x80000000u);
    d2u[p] = u;
    const unsigned long long kk = ((unsigned long long)u << 32) | (unsigned)p;
    if      (kk < best)  { second = best; best = kk; }
    else if (kk < second){ second = kk; }
  }
  __syncthreads();

  for (int it = 0; it < K2NN; ++it){
    const unsigned vb = (unsigned)(best >> 32);
    const unsigned wv = wave_min_u32(vb);
    const unsigned long long bal = __ballot(vb == wv);
    unsigned long long k;
    if (__popcll(bal) == 1){
      const int lane = __ffsll(bal) - 1;
      const unsigned lp = (unsigned)__shfl((int)(unsigned)best, lane);
      k = ((unsigned long long)wv << 32) | lp;
    } else {
      k = best;
      #pragma unroll
      for (int o = 32; o > 0; o >>= 1){
        const unsigned long long k2 = __shfl_xor(k, o);
        if (k2 < k) k = k2;
      }
    }
    if ((tid & 63) == 0) warr[it & 1][tid >> 6] = k;
    __syncthreads();
    unsigned long long kb = warr[it & 1][0];
    #pragma unroll
    for (int w = 1; w < 4; ++w){
      const unsigned long long k2 = warr[it & 1][w];
      if (k2 < kb) kb = k2;
    }
    const unsigned p = (unsigned)kb;
    if (tid == 0) ws_knn[(size_t)blk*K2NN + it] = (int)p;
    if (best == kb){
      d2u[p] = 0xFFFFFFFFu;
      best = second; second = ~0ULL;
      if (best == ~0ULL){
        #pragma unroll 4
        for (int j = 0; j < NPTS/256; ++j){
          const int q = tid + 256*j;
          const unsigned long long kk = ((unsigned long long)d2u[q] << 32) | (unsigned)q;
          if      (kk < best)  { second = best; best = kk; }
          else if (kk < second){ second = kk; }
        }
      }
    }
  }
}

// ---------------------------------------------------------------------------
// Kernel 3: fused EGNN per (b,m) (round-2 proven, unchanged).
// ---------------------------------------------------------------------------
#define S1STR 132

template<int KNB>
__device__ __forceinline__ void egnn_scale(
    int isc, int b, int m, int tid,
    const float* __restrict__ we1, const float* __restrict__ be1,
    const float* __restrict__ we2, const float* __restrict__ be2,
    const float* __restrict__ wxw, const float* __restrict__ bxw,
    const float* __restrict__ wh1, const float* __restrict__ bh1,
    const float* __restrict__ wh2, const float* __restrict__ bh2,
    const float* hi, const float (*hj)[NC], const float (*rel)[3],
    const float* d2s, float (*s1)[S1STR], float (*s2)[S1STR],
    float* coefs, float* aggs, float* t1,
    float cx, float cy, float cz, float* __restrict__ out)
{
  constexpr int KH = KNB/2;
  const int h  = tid & 127;
  const int jg = tid >> 7;
  const int j0 = jg * KH;
  const float* W1 = we1 + (size_t)isc*129*HH;
  const float* W2 = we2 + (size_t)isc*HH*HH;

  float shi = be1[isc*HH + h];
  for (int r = 0; r < NC; ++r) shi += hi[r] * W1[r*HH + h];
  float acc[KH];
  #pragma unroll
  for (int jl = 0; jl < KH; ++jl) acc[jl] = shi;
  for (int r4 = 0; r4 < NC/4; ++r4){
    const float w0 = W1[(NC + 4*r4+0)*HH + h];
    const float w1 = W1[(NC + 4*r4+1)*HH + h];
    const float w2 = W1[(NC + 4*r4+2)*HH + h];
    const float w3 = W1[(NC + 4*r4+3)*HH + h];
    #pragma unroll
    for (int jl = 0; jl < KH; ++jl){
      const float4 v = *(const float4*)&hj[j0+jl][4*r4];
      acc[jl] += v.x*w0; acc[jl] += v.y*w1; acc[jl] += v.z*w2; acc[jl] += v.w*w3;
    }
  }
  {
    const float wd = W1[128*HH + h];
    #pragma unroll
    for (int jl = 0; jl < KH; ++jl)
      s1[j0+jl][h] = silu_f(acc[jl] + d2s[j0+jl]*wd);
  }
  __syncthreads();

  float acc2[KH];
  {
    const float b2 = be2[isc*HH + h];
    #pragma unroll
    for (int jl = 0; jl < KH; ++jl) acc2[jl] = b2;
  }
  for (int r4 = 0; r4 < HH/4; ++r4){
    const float w0 = W2[(4*r4+0)*HH + h];
    const float w1 = W2[(4*r4+1)*HH + h];
    const float w2 = W2[(4*r4+2)*HH + h];
    const float w3 = W2[(4*r4+3)*HH + h];
    #pragma unroll
    for (int jl = 0; jl < KH; ++jl){
      const float4 v = *(const float4*)&s1[j0+jl][4*r4];
      acc2[jl] += v.x*w0; acc2[jl] += v.y*w1; acc2[jl] += v.z*w2; acc2[jl] += v.w*w3;
    }
  }
  #pragma unroll
  for (int jl = 0; jl < KH; ++jl)
    s2[j0+jl][h] = silu_f(acc2[jl]);
  __syncthreads();

  if (tid < HH){
    float a = 0.f;
    #pragma unroll
    for (int j = 0; j < KNB; ++j) a += s2[j][tid];
    aggs[tid] = a;
  } else if (tid < HH + KNB){
    const int j = tid - HH;
    const float* WX = wxw + isc*HH;
    float c = 0.f;
    for (int r = 0; r < HH; ++r) c += s2[j][r]*WX[r];
    coefs[j] = c + bxw[isc];
  }
  __syncthreads();

  if (tid < 3){
    float s = 0.f;
    #pragma unroll
    for (int j = 0; j < KNB; ++j) s += rel[j][tid]*coefs[j];
    const float cc = (tid==0) ? cx : ((tid==1) ? cy : cz);
    out[OUT1_OFF + ((size_t)(b*2 + isc)*MCENT + m)*3 + tid] = cc + s*(1.0f/KNB);
  }
  if (tid < HH){
    const float* WH1 = wh1 + (size_t)isc*(NC+HH)*HH;
    float n = bh1[isc*HH + tid];
    for (int r = 0; r < NC; ++r) n += hi[r]*WH1[r*HH + tid];
    for (int r = 0; r < HH; ++r) n += aggs[r]*WH1[(NC+r)*HH + tid];
    t1[tid] = silu_f(n);
  }
  __syncthreads();
  if (tid < HH){
    const float* WH2 = wh2 + (size_t)isc*HH*HH;
    float v = bh2[isc*HH + tid];
    for (int r = 0; r < HH; ++r) v += t1[r]*WH2[r*HH + tid];
    out[OUT2_OFF + ((size_t)(b*2*HH) + isc*HH + tid)*MCENT + m] = v;
  }
  __syncthreads();
}

__global__ __launch_bounds__(256) void egnn_kernel(
    const float* __restrict__ xyz,  const float* __restrict__ feat,
    const float* __restrict__ we1,  const float* __restrict__ be1,
    const float* __restrict__ we2,  const float* __restrict__ be2,
    const float* __restrict__ wxw,  const float* __restrict__ bxw,
    const float* __restrict__ wh1,  const float* __restrict__ bh1,
    const float* __restrict__ wh2,  const float* __restrict__ bh2,
    const int* __restrict__ ws_idx, const int* __restrict__ ws_knn,
    float* __restrict__ out)
{
  __shared__ __align__(16) float hi[NC];
  __shared__ __align__(16) float hj[K2NN][NC];
  __shared__ float rel[K2NN][3];
  __shared__ float d2s[K2NN];
  __shared__ __align__(16) float s1[K2NN][S1STR];
  __shared__ __align__(16) float s2[K2NN][S1STR];
  __shared__ float coefs[K2NN];
  __shared__ float aggs[HH];
  __shared__ float t1[HH];
  __shared__ int   nidx[K2NN];

  const int blk = blockIdx.x;
  const int b = blk / MCENT, m = blk % MCENT;
  const int tid = threadIdx.x;
  const float* P = xyz + (size_t)b*NPTS*3;
  const float cx = out[OUT0_OFF + (size_t)(b*MCENT+m)*3 + 0];
  const float cy = out[OUT0_OFF + (size_t)(b*MCENT+m)*3 + 1];
  const float cz = out[OUT0_OFF + (size_t)(b*MCENT+m)*3 + 2];

  const int ci = ws_idx[b*MCENT + m];
  if (tid < NC)   hi[tid]   = feat[((size_t)b*NC + tid)*NPTS + ci];
  if (tid < K2NN) nidx[tid] = ws_knn[(size_t)blk*K2NN + tid];
  __syncthreads();

  if (tid < K2NN){
    const int p = nidx[tid];
    const float rx = cx - P[p*3+0];
    const float ry = cy - P[p*3+1];
    const float rz = cz - P[p*3+2];
    rel[tid][0]=rx; rel[tid][1]=ry; rel[tid][2]=rz;
    d2s[tid] = rx*rx + ry*ry + rz*rz;
  }
  {
    const int j  = tid >> 3;
    const int c0 = (tid & 7) * 8;
    const int p  = nidx[j];
    #pragma unroll
    for (int q = 0; q < 8; ++q)
      hj[j][c0+q] = feat[((size_t)b*NC + c0 + q)*NPTS + p];
  }
  __syncthreads();

  egnn_scale<16>(0, b, m, tid, we1, be1, we2, be2, wxw, bxw, wh1, bh1, wh2, bh2,
                 hi, hj, rel, d2s, s1, s2, coefs, aggs, t1, cx, cy, cz, out);
  egnn_scale<32>(1, b, m, tid, we1, be1, we2, be2, wxw, bxw, wh1, bh1, wh2, bh2,
                 hi, hj, rel, d2s, s1, s2, coefs, aggs, t1, cx, cy, cz, out);
}

// ---------------------------------------------------------------------------
extern "C" void kernel_launch(void* const* d_in, const int* in_sizes, int n_in,
                              void* d_out, int out_size, void* d_ws, size_t ws_size,
                              hipStream_t stream){
  const float* xyz = (const float*)d_in[0];
  const float* feat= (const float*)d_in[1];
  const float* we1 = (const float*)d_in[2];
  const float* be1 = (const float*)d_in[3];
  const float* we2 = (const float*)d_in[4];
  const float* be2 = (const float*)d_in[5];
  const float* wxw = (const float*)d_in[6];
  const float* bxw = (const float*)d_in[7];
  const float* wh1 = (const float*)d_in[8];
  const float* bh1 = (const float*)d_in[9];
  const float* wh2 = (const float*)d_in[10];
  const float* bh2 = (const float*)d_in[11];
  float* out = (float*)d_out;

  int* ws_idx = (int*)d_ws;
  int* ws_knn = ws_idx + NB*MCENT;

  fps_kernel <<<dim3(NB),       dim3(512), 0, stream>>>(xyz, out, ws_idx);
  knn_kernel <<<dim3(NB*MCENT), dim3(256), 0, stream>>>(xyz, out, ws_knn);
  egnn_kernel<<<dim3(NB*MCENT), dim3(256), 0, stream>>>(xyz, feat,
      we1, be1, we2, be2, wxw, bxw, wh1, bh1, wh2, bh2, ws_idx, ws_knn, out);
}

// Round 9
// 2405.288 us; speedup vs baseline: 4.4226x; 1.7892x over previous
//
#include <hip/hip_runtime.h>
#include <stdint.h>
#include <math.h>

#define NPTS  8192
#define NB    2
#define NC    64
#define MCENT 2048
#define HH    128
#define K2NN  32

// float offsets inside d_out (outputs concatenated flat, all read as fp32)
#define OUT0_OFF 0                                   // dsamp_xyz (B,M,3)
#define OUT1_OFF (NB*MCENT*3)                        // shifted   (B,2M,3)
#define OUT2_OFF (OUT1_OFF + NB*2*MCENT*3)           // feats     (B,2*O,M)
#define OUT3_OFF (OUT2_OFF + NB*2*HH*MCENT)          // idx       (B,M) as float

__device__ __forceinline__ float silu_f(float v){ return v / (1.0f + expf(-v)); }

// ---- fast wave-wide u32 butterfly reduce: 4x DPP + swizzle(xor16) + shfl(xor32)
template<int CTRL>
__device__ __forceinline__ unsigned dppmov(unsigned v){
  return (unsigned)__builtin_amdgcn_update_dpp(0, (int)v, CTRL, 0xF, 0xF, true);
}
__device__ __forceinline__ unsigned wave_max_u32(unsigned v){
  unsigned s;
  s = dppmov<0xB1>(v);  v = v > s ? v : s;   // quad_perm xor1
  s = dppmov<0x4E>(v);  v = v > s ? v : s;   // quad_perm xor2
  s = dppmov<0x141>(v); v = v > s ? v : s;   // row_half_mirror = xor4
  s = dppmov<0x140>(v); v = v > s ? v : s;   // row_mirror      = xor8
  s = (unsigned)__builtin_amdgcn_ds_swizzle((int)v, 0x401F); v = v > s ? v : s; // xor16
  s = (unsigned)__shfl_xor((int)v, 32); v = v > s ? v : s;                      // xor32
  return v;
}
__device__ __forceinline__ unsigned wave_min_u32(unsigned v){
  unsigned s;
  s = dppmov<0xB1>(v);  v = v < s ? v : s;
  s = dppmov<0x4E>(v);  v = v < s ? v : s;
  s = dppmov<0x141>(v); v = v < s ? v : s;
  s = dppmov<0x140>(v); v = v < s ? v : s;
  s = (unsigned)__builtin_amdgcn_ds_swizzle((int)v, 0x401F); v = v < s ? v : s;
  s = (unsigned)__shfl_xor((int)v, 32); v = v < s ? v : s;
  return v;
}

// LDS-only barrier: order LDS producer->consumer across the block WITHOUT
// draining the vector-memory store queue (publish stores stay in flight;
// they are never read back inside the kernel, kernel-end drain handles
// visibility for the following kernels). Proven correct over 2047 iters (r8).
__device__ __forceinline__ void bar_lds(){
  asm volatile("s_waitcnt lgkmcnt(0)" ::: "memory");
  __builtin_amdgcn_s_barrier();
  __builtin_amdgcn_sched_barrier(0);
}

// ---------------------------------------------------------------------------
// Kernel 1: farthest point sampling. One block per batch, 512 thr x 16 pts in
// registers + 96KB LDS mirror for winner broadcast. One LDS-only barrier/iter
// (double-buffered warr), DPP value-reduce + ballot (lowest lane = lowest
// point index under blocked assignment), publish stores never drained in-loop.
// Exact reference semantics: contract off, numpy op order, first-max index.
// ---------------------------------------------------------------------------
__global__ __launch_bounds__(512, 2) void fps_kernel(const float* __restrict__ xyz,
                                                     float* __restrict__ out,
                                                     int* __restrict__ ws_idx){
#pragma clang fp contract(off)
  __shared__ float xs[NPTS], ys[NPTS], zs[NPTS];      // 96 KB mirror
  __shared__ unsigned long long warr[2][8];
  const int b    = blockIdx.x;
  const int tid  = threadIdx.x;
  const int lane = tid & 63, wid = tid >> 6;
  const float* P = xyz + (size_t)b * NPTS * 3;

  float x[16], y[16], z[16], mind[16];
  #pragma unroll
  for (int j = 0; j < 16; ++j){
    const int p = tid*16 + j;
    const float px = P[p*3+0], py = P[p*3+1], pz = P[p*3+2];
    x[j] = px; y[j] = py; z[j] = pz; mind[j] = 1e10f;
    xs[p] = px; ys[p] = py; zs[p] = pz;
  }
  float cx = P[0], cy = P[1], cz = P[2];
  if (tid == 0){
    ws_idx[b*MCENT] = 0;
    out[OUT3_OFF + b*MCENT] = 0.0f;
    out[OUT0_OFF + (size_t)(b*MCENT)*3 + 0] = cx;
    out[OUT0_OFF + (size_t)(b*MCENT)*3 + 1] = cy;
    out[OUT0_OFF + (size_t)(b*MCENT)*3 + 2] = cz;
  }
  __syncthreads();   // one full barrier at init is fine

  for (int t = 1; t < MCENT; ++t){
    // ---- distance + min update + running first-argmax (reference op order)
    float bestv = -1.0f; int bestp = tid*16;
    #pragma unroll
    for (int j = 0; j < 16; ++j){
      const float dx = x[j]-cx, dy = y[j]-cy, dz = z[j]-cz;
      const float d  = (dx*dx + dy*dy) + dz*dz;   // contract off: per-op rounding
      const float mn = fminf(mind[j], d);
      mind[j] = mn;
      if (mn > bestv){ bestv = mn; bestp = tid*16 + j; }  // strict > keeps first
    }
    // ---- wave reduce: u32 value max (bestv>=0 -> u32 order == f32 order),
    // ballot -> lowest tied lane = lowest point range (blocked assignment).
    const unsigned vb = __float_as_uint(bestv);
    const unsigned wv = wave_max_u32(vb);
    const unsigned long long bal = __ballot(vb == wv);
    const int wl = __ffsll(bal) - 1;
    const int wp = __shfl(bestp, wl);
    if (lane == 0)
      warr[t & 1][wid] = ((unsigned long long)wv << 32) | (unsigned)(NPTS-1-wp);
    bar_lds();                                    // only barrier in the loop
    // ---- block reduce over 8 wave keys (ties -> larger (N-1-p) = smaller p)
    unsigned long long kb = warr[t & 1][0];
    #pragma unroll
    for (int w = 1; w < 8; ++w){
      const unsigned long long k2 = warr[t & 1][w];
      if (k2 > kb) kb = k2;
    }
    const int p = NPTS - 1 - (int)(kb & 0xFFFFFFFFULL);
    cx = xs[p]; cy = ys[p]; cz = zs[p];           // uniform broadcast reads
    if (tid == 0){                                 // fire-and-forget publishes
      ws_idx[b*MCENT + t] = p;
      out[OUT3_OFF + b*MCENT + t] = (float)p;
      out[OUT0_OFF + (size_t)(b*MCENT + t)*3 + 0] = cx;
      out[OUT0_OFF + (size_t)(b*MCENT + t)*3 + 1] = cy;
      out[OUT0_OFF + (size_t)(b*MCENT + t)*3 + 2] = cz;
    }
  }
}

// ---------------------------------------------------------------------------
// Kernel 2: exact 32-NN per center, ascending by (d2, idx); first 16 = 16-NN.
// Per-thread top-2 cache avoids the serial owner rescan on most removals.
// (round-2 proven, unchanged)
// ---------------------------------------------------------------------------
__global__ __launch_bounds__(256) void knn_kernel(const float* __restrict__ xyz,
                                                  const float* __restrict__ out,
                                                  int* __restrict__ ws_knn){
#pragma clang fp contract(off)
  __shared__ unsigned d2u[NPTS];          // monotonic-transformed d2 bits
  __shared__ unsigned long long warr[2][4];
  const int blk = blockIdx.x;
  const int b = blk / MCENT, m = blk % MCENT;
  const int tid = threadIdx.x;
  const float* P = xyz + (size_t)b*NPTS*3;
  const float cx = out[OUT0_OFF + (size_t)(b*MCENT+m)*3 + 0];
  const float cy = out[OUT0_OFF + (size_t)(b*MCENT+m)*3 + 1];
  const float cz = out[OUT0_OFF + (size_t)(b*MCENT+m)*3 + 2];
  const float cn = (cx*cx + cy*cy) + cz*cz;

  unsigned long long best = ~0ULL, second = ~0ULL;
  #pragma unroll 4
  for (int j = 0; j < NPTS/256; ++j){
    const int p = tid + 256*j;
    const float px = P[p*3+0], py = P[p*3+1], pz = P[p*3+2];
    const float pn = (px*px + py*py) + pz*pz;
    const float e  = (cx*px + cy*py) + cz*pz;
    const float d2 = (cn + pn) - 2.0f*e;           // reference formula / op order
    unsigned u = __float_as_uint(d2);
    u = (u & 0x80000000u) ? ~u : (u | 0x80000000u);
    d2u[p] = u;
    const unsigned long long kk = ((unsigned long long)u << 32) | (unsigned)p;
    if      (kk < best)  { second = best; best = kk; }
    else if (kk < second){ second = kk; }
  }
  __syncthreads();

  for (int it = 0; it < K2NN; ++it){
    const unsigned vb = (unsigned)(best >> 32);
    const unsigned wv = wave_min_u32(vb);
    const unsigned long long bal = __ballot(vb == wv);
    unsigned long long k;
    if (__popcll(bal) == 1){
      const int lane = __ffsll(bal) - 1;
      const unsigned lp = (unsigned)__shfl((int)(unsigned)best, lane);  // low32 = p
      k = ((unsigned long long)wv << 32) | lp;
    } else {
      // exact fallback: u64 (value,idx) min butterfly (rare value tie in wave)
      k = best;
      #pragma unroll
      for (int o = 32; o > 0; o >>= 1){
        const unsigned long long k2 = __shfl_xor(k, o);
        if (k2 < k) k = k2;
      }
    }
    if ((tid & 63) == 0) warr[it & 1][tid >> 6] = k;
    __syncthreads();
    unsigned long long kb = warr[it & 1][0];
    #pragma unroll
    for (int w = 1; w < 4; ++w){
      const unsigned long long k2 = warr[it & 1][w];
      if (k2 < kb) kb = k2;                        // u64 min: ties pick min p
    }
    const unsigned p = (unsigned)kb;
    if (tid == 0) ws_knn[(size_t)blk*K2NN + it] = (int)p;
    if (best == kb){                               // unique owner (keys unique by p)
      d2u[p] = 0xFFFFFFFFu;                        // mark removed (own partition)
      best = second; second = ~0ULL;
      if (best == ~0ULL){                          // top-2 exhausted: rescan own part
        #pragma unroll 4
        for (int j = 0; j < NPTS/256; ++j){
          const int q = tid + 256*j;
          const unsigned long long kk = ((unsigned long long)d2u[q] << 32) | (unsigned)q;
          if      (kk < best)  { second = best; best = kk; }
          else if (kk < second){ second = kk; }
        }
      }
    }
  }
}

// ---------------------------------------------------------------------------
// Kernel 3: fused EGNN per (b,m) (round-2 proven, unchanged).
// ---------------------------------------------------------------------------
#define S1STR 132   // padded row stride: 16B-aligned float4, decorrelated banks

template<int KNB>
__device__ __forceinline__ void egnn_scale(
    int isc, int b, int m, int tid,
    const float* __restrict__ we1, const float* __restrict__ be1,
    const float* __restrict__ we2, const float* __restrict__ be2,
    const float* __restrict__ wxw, const float* __restrict__ bxw,
    const float* __restrict__ wh1, const float* __restrict__ bh1,
    const float* __restrict__ wh2, const float* __restrict__ bh2,
    const float* hi, const float (*hj)[NC], const float (*rel)[3],
    const float* d2s, float (*s1)[S1STR], float (*s2)[S1STR],
    float* coefs, float* aggs, float* t1,
    float cx, float cy, float cz, float* __restrict__ out)
{
  constexpr int KH = KNB/2;
  const int h  = tid & 127;
  const int jg = tid >> 7;
  const int j0 = jg * KH;
  const float* W1 = we1 + (size_t)isc*129*HH;
  const float* W2 = we2 + (size_t)isc*HH*HH;

  // ---- edge layer 1: [h_i, h_j, d2] @ we1 + be1, silu
  float shi = be1[isc*HH + h];
  for (int r = 0; r < NC; ++r) shi += hi[r] * W1[r*HH + h];   // h_i part: shared by all j
  float acc[KH];
  #pragma unroll
  for (int jl = 0; jl < KH; ++jl) acc[jl] = shi;
  for (int r4 = 0; r4 < NC/4; ++r4){
    const float w0 = W1[(NC + 4*r4+0)*HH + h];
    const float w1 = W1[(NC + 4*r4+1)*HH + h];
    const float w2 = W1[(NC + 4*r4+2)*HH + h];
    const float w3 = W1[(NC + 4*r4+3)*HH + h];
    #pragma unroll
    for (int jl = 0; jl < KH; ++jl){
      const float4 v = *(const float4*)&hj[j0+jl][4*r4];
      acc[jl] += v.x*w0; acc[jl] += v.y*w1; acc[jl] += v.z*w2; acc[jl] += v.w*w3;
    }
  }
  {
    const float wd = W1[128*HH + h];
    #pragma unroll
    for (int jl = 0; jl < KH; ++jl)
      s1[j0+jl][h] = silu_f(acc[jl] + d2s[j0+jl]*wd);
  }
  __syncthreads();

  // ---- edge layer 2: @ we2 + be2, silu
  float acc2[KH];
  {
    const float b2 = be2[isc*HH + h];
    #pragma unroll
    for (int jl = 0; jl < KH; ++jl) acc2[jl] = b2;
  }
  for (int r4 = 0; r4 < HH/4; ++r4){
    const float w0 = W2[(4*r4+0)*HH + h];
    const float w1 = W2[(4*r4+1)*HH + h];
    const float w2 = W2[(4*r4+2)*HH + h];
    const float w3 = W2[(4*r4+3)*HH + h];
    #pragma unroll
    for (int jl = 0; jl < KH; ++jl){
      const float4 v = *(const float4*)&s1[j0+jl][4*r4];
      acc2[jl] += v.x*w0; acc2[jl] += v.y*w1; acc2[jl] += v.z*w2; acc2[jl] += v.w*w3;
    }
  }
  #pragma unroll
  for (int jl = 0; jl < KH; ++jl)
    s2[j0+jl][h] = silu_f(acc2[jl]);
  __syncthreads();

  // ---- agg over j (threads 0..127) and coef per j (threads 128..128+KNB)
  if (tid < HH){
    float a = 0.f;
    #pragma unroll
    for (int j = 0; j < KNB; ++j) a += s2[j][tid];
    aggs[tid] = a;
  } else if (tid < HH + KNB){
    const int j = tid - HH;
    const float* WX = wxw + isc*HH;
    float c = 0.f;
    for (int r = 0; r < HH; ++r) c += s2[j][r]*WX[r];
    coefs[j] = c + bxw[isc];
  }
  __syncthreads();

  // ---- coordinate shift output
  if (tid < 3){
    float s = 0.f;
    #pragma unroll
    for (int j = 0; j < KNB; ++j) s += rel[j][tid]*coefs[j];
    const float cc = (tid==0) ? cx : ((tid==1) ? cy : cz);
    out[OUT1_OFF + ((size_t)(b*2 + isc)*MCENT + m)*3 + tid] = cc + s*(1.0f/KNB);
  }

  // ---- node MLP layer 1: [h_i, agg] @ wh1 + bh1, silu
  if (tid < HH){
    const float* WH1 = wh1 + (size_t)isc*(NC+HH)*HH;
    float n = bh1[isc*HH + tid];
    for (int r = 0; r < NC; ++r) n += hi[r]*WH1[r*HH + tid];
    for (int r = 0; r < HH; ++r) n += aggs[r]*WH1[(NC+r)*HH + tid];
    t1[tid] = silu_f(n);
  }
  __syncthreads();

  // ---- node MLP layer 2 (no activation)
  if (tid < HH){
    const float* WH2 = wh2 + (size_t)isc*HH*HH;
    float v = bh2[isc*HH + tid];
    for (int r = 0; r < HH; ++r) v += t1[r]*WH2[r*HH + tid];
    out[OUT2_OFF + ((size_t)(b*2*HH) + isc*HH + tid)*MCENT + m] = v;
  }
  __syncthreads();  // before next scale reuses s1/s2/aggs/t1/coefs
}

__global__ __launch_bounds__(256) void egnn_kernel(
    const float* __restrict__ xyz,  const float* __restrict__ feat,
    const float* __restrict__ we1,  const float* __restrict__ be1,
    const float* __restrict__ we2,  const float* __restrict__ be2,
    const float* __restrict__ wxw,  const float* __restrict__ bxw,
    const float* __restrict__ wh1,  const float* __restrict__ bh1,
    const float* __restrict__ wh2,  const float* __restrict__ bh2,
    const int* __restrict__ ws_idx, const int* __restrict__ ws_knn,
    float* __restrict__ out)
{
  __shared__ __align__(16) float hi[NC];
  __shared__ __align__(16) float hj[K2NN][NC];
  __shared__ float rel[K2NN][3];
  __shared__ float d2s[K2NN];
  __shared__ __align__(16) float s1[K2NN][S1STR];
  __shared__ __align__(16) float s2[K2NN][S1STR];
  __shared__ float coefs[K2NN];
  __shared__ float aggs[HH];
  __shared__ float t1[HH];
  __shared__ int   nidx[K2NN];

  const int blk = blockIdx.x;
  const int b = blk / MCENT, m = blk % MCENT;
  const int tid = threadIdx.x;
  const float* P = xyz + (size_t)b*NPTS*3;
  const float cx = out[OUT0_OFF + (size_t)(b*MCENT+m)*3 + 0];
  const float cy = out[OUT0_OFF + (size_t)(b*MCENT+m)*3 + 1];
  const float cz = out[OUT0_OFF + (size_t)(b*MCENT+m)*3 + 2];

  const int ci = ws_idx[b*MCENT + m];
  if (tid < NC)   hi[tid]   = feat[((size_t)b*NC + tid)*NPTS + ci];
  if (tid < K2NN) nidx[tid] = ws_knn[(size_t)blk*K2NN + tid];
  __syncthreads();

  if (tid < K2NN){
    const int p = nidx[tid];
    const float rx = cx - P[p*3+0];
    const float ry = cy - P[p*3+1];
    const float rz = cz - P[p*3+2];
    rel[tid][0]=rx; rel[tid][1]=ry; rel[tid][2]=rz;
    d2s[tid] = rx*rx + ry*ry + rz*rz;
  }
  {
    const int j  = tid >> 3;
    const int c0 = (tid & 7) * 8;
    const int p  = nidx[j];
    #pragma unroll
    for (int q = 0; q < 8; ++q)
      hj[j][c0+q] = feat[((size_t)b*NC + c0 + q)*NPTS + p];
  }
  __syncthreads();

  egnn_scale<16>(0, b, m, tid, we1, be1, we2, be2, wxw, bxw, wh1, bh1, wh2, bh2,
                 hi, hj, rel, d2s, s1, s2, coefs, aggs, t1, cx, cy, cz, out);
  egnn_scale<32>(1, b, m, tid, we1, be1, we2, be2, wxw, bxw, wh1, bh1, wh2, bh2,
                 hi, hj, rel, d2s, s1, s2, coefs, aggs, t1, cx, cy, cz, out);
}

// ---------------------------------------------------------------------------
extern "C" void kernel_launch(void* const* d_in, const int* in_sizes, int n_in,
                              void* d_out, int out_size, void* d_ws, size_t ws_size,
                              hipStream_t stream){
  const float* xyz = (const float*)d_in[0];
  const float* feat= (const float*)d_in[1];
  const float* we1 = (const float*)d_in[2];
  const float* be1 = (const float*)d_in[3];
  const float* we2 = (const float*)d_in[4];
  const float* be2 = (const float*)d_in[5];
  const float* wxw = (const float*)d_in[6];
  const float* bxw = (const float*)d_in[7];
  const float* wh1 = (const float*)d_in[8];
  const float* bh1 = (const float*)d_in[9];
  const float* wh2 = (const float*)d_in[10];
  const float* bh2 = (const float*)d_in[11];
  float* out = (float*)d_out;

  // workspace: idx (B*M int) + knn (B*M*32 int) = 528 KB
  int* ws_idx = (int*)d_ws;
  int* ws_knn = ws_idx + NB*MCENT;

  fps_kernel <<<dim3(NB),        dim3(512), 0, stream>>>(xyz, out, ws_idx);
  knn_kernel <<<dim3(NB*MCENT),  dim3(256), 0, stream>>>(xyz, out, ws_knn);
  egnn_kernel<<<dim3(NB*MCENT),  dim3(256), 0, stream>>>(xyz, feat,
      we1, be1, we2, be2, wxw, bxw, wh1, bh1, wh2, bh2, ws_idx, ws_knn, out);
}

// Round 10
// 2383.578 us; speedup vs baseline: 4.4628x; 1.0091x over previous
//
#include <hip/hip_runtime.h>
#include <stdint.h>
#include <math.h>

#define NPTS  8192
#define NB    2
#define NC    64
#define MCENT 2048
#define HH    128
#define K2NN  32

// float offsets inside d_out (outputs concatenated flat, all read as fp32)
#define OUT0_OFF 0                                   // dsamp_xyz (B,M,3)
#define OUT1_OFF (NB*MCENT*3)                        // shifted   (B,2M,3)
#define OUT2_OFF (OUT1_OFF + NB*2*MCENT*3)           // feats     (B,2*O,M)
#define OUT3_OFF (OUT2_OFF + NB*2*HH*MCENT)          // idx       (B,M) as float

__device__ __forceinline__ float silu_f(float v){ return v / (1.0f + expf(-v)); }

// ---- LDS-free full-wave reduce: DPP xor1/2/4/8 + row_bcast15/31 + readlane.
// update_dpp with old=v -> lanes not targeted by the pattern keep v (identity
// for both max and min). Lane 63 ends with the full 64-lane result; readlane
// broadcasts it via SGPR. No ds_swizzle / ds_bpermute on the critical path.
template<int CTRL>
__device__ __forceinline__ unsigned dppk(unsigned v){
  return (unsigned)__builtin_amdgcn_update_dpp((int)v, (int)v, CTRL, 0xF, 0xF, false);
}
__device__ __forceinline__ unsigned wave_max_u32_sgpr(unsigned v){
  unsigned s;
  s = dppk<0xB1>(v);  v = v > s ? v : s;   // quad_perm xor1
  s = dppk<0x4E>(v);  v = v > s ? v : s;   // quad_perm xor2
  s = dppk<0x141>(v); v = v > s ? v : s;   // row_half_mirror (xor4)
  s = dppk<0x140>(v); v = v > s ? v : s;   // row_mirror      (xor8) -> row-local max
  s = dppk<0x142>(v); v = v > s ? v : s;   // row_bcast15: row1=r0|r1, row3=r2|r3
  s = dppk<0x143>(v); v = v > s ? v : s;   // row_bcast31: row3=full wave
  return (unsigned)__builtin_amdgcn_readlane((int)v, 63);  // uniform (SGPR)
}
__device__ __forceinline__ unsigned wave_min_u32_sgpr(unsigned v){
  unsigned s;
  s = dppk<0xB1>(v);  v = v < s ? v : s;
  s = dppk<0x4E>(v);  v = v < s ? v : s;
  s = dppk<0x141>(v); v = v < s ? v : s;
  s = dppk<0x140>(v); v = v < s ? v : s;
  s = dppk<0x142>(v); v = v < s ? v : s;
  s = dppk<0x143>(v); v = v < s ? v : s;
  return (unsigned)__builtin_amdgcn_readlane((int)v, 63);
}

// LDS-only barrier: order LDS producer->consumer across the block WITHOUT
// draining the vector-memory store queue (publish stores stay in flight;
// never read back in-kernel; kernel-end drain covers later kernels).
__device__ __forceinline__ void bar_lds(){
  asm volatile("s_waitcnt lgkmcnt(0)" ::: "memory");
  __builtin_amdgcn_s_barrier();
  __builtin_amdgcn_sched_barrier(0);
}

// ---------------------------------------------------------------------------
// Kernel 1: farthest point sampling. One block per batch, 512 thr x 16 pts in
// registers + 96KB LDS mirror for winner broadcast. One LDS-only barrier/iter,
// fully-VALU wave reduce (DPP+readlane), readlane instead of shuffle for the
// winner index. Exact reference semantics: contract off, numpy op order,
// first-max index (ballot lowest lane = lowest point, blocked assignment).
// ---------------------------------------------------------------------------
__global__ __launch_bounds__(512, 2) void fps_kernel(const float* __restrict__ xyz,
                                                     float* __restrict__ out,
                                                     int* __restrict__ ws_idx){
#pragma clang fp contract(off)
  __shared__ float xs[NPTS], ys[NPTS], zs[NPTS];      // 96 KB mirror
  __shared__ unsigned long long warr[2][8];
  const int b    = blockIdx.x;
  const int tid  = threadIdx.x;
  const int lane = tid & 63, wid = tid >> 6;
  const float* P = xyz + (size_t)b * NPTS * 3;

  float x[16], y[16], z[16], mind[16];
  #pragma unroll
  for (int j = 0; j < 16; ++j){
    const int p = tid*16 + j;
    const float px = P[p*3+0], py = P[p*3+1], pz = P[p*3+2];
    x[j] = px; y[j] = py; z[j] = pz; mind[j] = 1e10f;
    xs[p] = px; ys[p] = py; zs[p] = pz;
  }
  float cx = P[0], cy = P[1], cz = P[2];
  if (tid == 0){
    ws_idx[b*MCENT] = 0;
    out[OUT3_OFF + b*MCENT] = 0.0f;
    out[OUT0_OFF + (size_t)(b*MCENT)*3 + 0] = cx;
    out[OUT0_OFF + (size_t)(b*MCENT)*3 + 1] = cy;
    out[OUT0_OFF + (size_t)(b*MCENT)*3 + 2] = cz;
  }
  __syncthreads();

  for (int t = 1; t < MCENT; ++t){
    // ---- distance + min update + running first-argmax (reference op order)
    float bestv = -1.0f; int bestp = tid*16;
    #pragma unroll
    for (int j = 0; j < 16; ++j){
      const float dx = x[j]-cx, dy = y[j]-cy, dz = z[j]-cz;
      const float d  = (dx*dx + dy*dy) + dz*dz;   // contract off: per-op rounding
      const float mn = fminf(mind[j], d);
      mind[j] = mn;
      if (mn > bestv){ bestv = mn; bestp = tid*16 + j; }  // strict > keeps first
    }
    // ---- LDS-free wave reduce (bestv>=0 -> u32 order == f32 order)
    const unsigned vb = __float_as_uint(bestv);
    const unsigned wv = wave_max_u32_sgpr(vb);            // SGPR broadcast
    const unsigned long long bal = __ballot(vb == wv);
    const int wl = __ffsll(bal) - 1;                      // lowest lane = lowest p
    const int wp = __builtin_amdgcn_readlane(bestp, wl);  // SGPR, no bpermute
    if (lane == 0)
      warr[t & 1][wid] = ((unsigned long long)wv << 32) | (unsigned)(NPTS-1-wp);
    bar_lds();                                    // only barrier in the loop
    // ---- block reduce over 8 wave keys (ties -> larger (N-1-p) = smaller p)
    unsigned long long kb = warr[t & 1][0];
    #pragma unroll
    for (int w = 1; w < 8; ++w){
      const unsigned long long k2 = warr[t & 1][w];
      if (k2 > kb) kb = k2;
    }
    const int p = NPTS - 1 - (int)(kb & 0xFFFFFFFFULL);
    cx = xs[p]; cy = ys[p]; cz = zs[p];           // uniform broadcast reads
    if (tid == 0){                                 // fire-and-forget publishes
      ws_idx[b*MCENT + t] = p;
      out[OUT3_OFF + b*MCENT + t] = (float)p;
      out[OUT0_OFF + (size_t)(b*MCENT + t)*3 + 0] = cx;
      out[OUT0_OFF + (size_t)(b*MCENT + t)*3 + 1] = cy;
      out[OUT0_OFF + (size_t)(b*MCENT + t)*3 + 2] = cz;
    }
  }
}

// ---------------------------------------------------------------------------
// Kernel 2: exact 32-NN per center, ascending by (d2, idx); first 16 = 16-NN.
// Per-thread top-2 cache; LDS-free value min-reduce (same DPP mechanism).
// ---------------------------------------------------------------------------
__global__ __launch_bounds__(256) void knn_kernel(const float* __restrict__ xyz,
                                                  const float* __restrict__ out,
                                                  int* __restrict__ ws_knn){
#pragma clang fp contract(off)
  __shared__ unsigned d2u[NPTS];          // monotonic-transformed d2 bits
  __shared__ unsigned long long warr[2][4];
  const int blk = blockIdx.x;
  const int b = blk / MCENT, m = blk % MCENT;
  const int tid = threadIdx.x;
  const float* P = xyz + (size_t)b*NPTS*3;
  const float cx = out[OUT0_OFF + (size_t)(b*MCENT+m)*3 + 0];
  const float cy = out[OUT0_OFF + (size_t)(b*MCENT+m)*3 + 1];
  const float cz = out[OUT0_OFF + (size_t)(b*MCENT+m)*3 + 2];
  const float cn = (cx*cx + cy*cy) + cz*cz;

  unsigned long long best = ~0ULL, second = ~0ULL;
  #pragma unroll 4
  for (int j = 0; j < NPTS/256; ++j){
    const int p = tid + 256*j;
    const float px = P[p*3+0], py = P[p*3+1], pz = P[p*3+2];
    const float pn = (px*px + py*py) + pz*pz;
    const float e  = (cx*px + cy*py) + cz*pz;
    const float d2 = (cn + pn) - 2.0f*e;           // reference formula / op order
    unsigned u = __float_as_uint(d2);
    u = (u & 0x80000000u) ? ~u : (u | 0x80000000u);
    d2u[p] = u;
    const unsigned long long kk = ((unsigned long long)u << 32) | (unsigned)p;
    if      (kk < best)  { second = best; best = kk; }
    else if (kk < second){ second = kk; }
  }
  __syncthreads();

  for (int it = 0; it < K2NN; ++it){
    const unsigned vb = (unsigned)(best >> 32);
    const unsigned wv = wave_min_u32_sgpr(vb);
    const unsigned long long bal = __ballot(vb == wv);
    unsigned long long k;
    if (__popcll(bal) == 1){
      const int wl = __ffsll(bal) - 1;
      const unsigned lp = (unsigned)__builtin_amdgcn_readlane((int)(unsigned)best, wl);
      k = ((unsigned long long)wv << 32) | lp;     // low32 = p
    } else {
      // exact fallback: u64 (value,idx) min butterfly (rare value tie in wave)
      k = best;
      #pragma unroll
      for (int o = 32; o > 0; o >>= 1){
        const unsigned long long k2 = __shfl_xor(k, o);
        if (k2 < k) k = k2;
      }
    }
    if ((tid & 63) == 0) warr[it & 1][tid >> 6] = k;
    __syncthreads();
    unsigned long long kb = warr[it & 1][0];
    #pragma unroll
    for (int w = 1; w < 4; ++w){
      const unsigned long long k2 = warr[it & 1][w];
      if (k2 < kb) kb = k2;                        // u64 min: ties pick min p
    }
    const unsigned p = (unsigned)kb;
    if (tid == 0) ws_knn[(size_t)blk*K2NN + it] = (int)p;
    if (best == kb){                               // unique owner (keys unique by p)
      d2u[p] = 0xFFFFFFFFu;                        // mark removed (own partition)
      best = second; second = ~0ULL;
      if (best == ~0ULL){                          // top-2 exhausted: rescan own part
        #pragma unroll 4
        for (int j = 0; j < NPTS/256; ++j){
          const int q = tid + 256*j;
          const unsigned long long kk = ((unsigned long long)d2u[q] << 32) | (unsigned)q;
          if      (kk < best)  { second = best; best = kk; }
          else if (kk < second){ second = kk; }
        }
      }
    }
  }
}

// ---------------------------------------------------------------------------
// Kernel 3: fused EGNN per (b,m) (round-2 proven, unchanged).
// ---------------------------------------------------------------------------
#define S1STR 132   // padded row stride: 16B-aligned float4, decorrelated banks

template<int KNB>
__device__ __forceinline__ void egnn_scale(
    int isc, int b, int m, int tid,
    const float* __restrict__ we1, const float* __restrict__ be1,
    const float* __restrict__ we2, const float* __restrict__ be2,
    const float* __restrict__ wxw, const float* __restrict__ bxw,
    const float* __restrict__ wh1, const float* __restrict__ bh1,
    const float* __restrict__ wh2, const float* __restrict__ bh2,
    const float* hi, const float (*hj)[NC], const float (*rel)[3],
    const float* d2s, float (*s1)[S1STR], float (*s2)[S1STR],
    float* coefs, float* aggs, float* t1,
    float cx, float cy, float cz, float* __restrict__ out)
{
  constexpr int KH = KNB/2;
  const int h  = tid & 127;
  const int jg = tid >> 7;
  const int j0 = jg * KH;
  const float* W1 = we1 + (size_t)isc*129*HH;
  const float* W2 = we2 + (size_t)isc*HH*HH;

  // ---- edge layer 1: [h_i, h_j, d2] @ we1 + be1, silu
  float shi = be1[isc*HH + h];
  for (int r = 0; r < NC; ++r) shi += hi[r] * W1[r*HH + h];   // h_i part: shared by all j
  float acc[KH];
  #pragma unroll
  for (int jl = 0; jl < KH; ++jl) acc[jl] = shi;
  for (int r4 = 0; r4 < NC/4; ++r4){
    const float w0 = W1[(NC + 4*r4+0)*HH + h];
    const float w1 = W1[(NC + 4*r4+1)*HH + h];
    const float w2 = W1[(NC + 4*r4+2)*HH + h];
    const float w3 = W1[(NC + 4*r4+3)*HH + h];
    #pragma unroll
    for (int jl = 0; jl < KH; ++jl){
      const float4 v = *(const float4*)&hj[j0+jl][4*r4];
      acc[jl] += v.x*w0; acc[jl] += v.y*w1; acc[jl] += v.z*w2; acc[jl] += v.w*w3;
    }
  }
  {
    const float wd = W1[128*HH + h];
    #pragma unroll
    for (int jl = 0; jl < KH; ++jl)
      s1[j0+jl][h] = silu_f(acc[jl] + d2s[j0+jl]*wd);
  }
  __syncthreads();

  // ---- edge layer 2: @ we2 + be2, silu
  float acc2[KH];
  {
    const float b2 = be2[isc*HH + h];
    #pragma unroll
    for (int jl = 0; jl < KH; ++jl) acc2[jl] = b2;
  }
  for (int r4 = 0; r4 < HH/4; ++r4){
    const float w0 = W2[(4*r4+0)*HH + h];
    const float w1 = W2[(4*r4+1)*HH + h];
    const float w2 = W2[(4*r4+2)*HH + h];
    const float w3 = W2[(4*r4+3)*HH + h];
    #pragma unroll
    for (int jl = 0; jl < KH; ++jl){
      const float4 v = *(const float4*)&s1[j0+jl][4*r4];
      acc2[jl] += v.x*w0; acc2[jl] += v.y*w1; acc2[jl] += v.z*w2; acc2[jl] += v.w*w3;
    }
  }
  #pragma unroll
  for (int jl = 0; jl < KH; ++jl)
    s2[j0+jl][h] = silu_f(acc2[jl]);
  __syncthreads();

  // ---- agg over j (threads 0..127) and coef per j (threads 128..128+KNB)
  if (tid < HH){
    float a = 0.f;
    #pragma unroll
    for (int j = 0; j < KNB; ++j) a += s2[j][tid];
    aggs[tid] = a;
  } else if (tid < HH + KNB){
    const int j = tid - HH;
    const float* WX = wxw + isc*HH;
    float c = 0.f;
    for (int r = 0; r < HH; ++r) c += s2[j][r]*WX[r];
    coefs[j] = c + bxw[isc];
  }
  __syncthreads();

  // ---- coordinate shift output
  if (tid < 3){
    float s = 0.f;
    #pragma unroll
    for (int j = 0; j < KNB; ++j) s += rel[j][tid]*coefs[j];
    const float cc = (tid==0) ? cx : ((tid==1) ? cy : cz);
    out[OUT1_OFF + ((size_t)(b*2 + isc)*MCENT + m)*3 + tid] = cc + s*(1.0f/KNB);
  }

  // ---- node MLP layer 1: [h_i, agg] @ wh1 + bh1, silu
  if (tid < HH){
    const float* WH1 = wh1 + (size_t)isc*(NC+HH)*HH;
    float n = bh1[isc*HH + tid];
    for (int r = 0; r < NC; ++r) n += hi[r]*WH1[r*HH + tid];
    for (int r = 0; r < HH; ++r) n += aggs[r]*WH1[(NC+r)*HH + tid];
    t1[tid] = silu_f(n);
  }
  __syncthreads();

  // ---- node MLP layer 2 (no activation)
  if (tid < HH){
    const float* WH2 = wh2 + (size_t)isc*HH*HH;
    float v = bh2[isc*HH + tid];
    for (int r = 0; r < HH; ++r) v += t1[r]*WH2[r*HH + tid];
    out[OUT2_OFF + ((size_t)(b*2*HH) + isc*HH + tid)*MCENT + m] = v;
  }
  __syncthreads();  // before next scale reuses s1/s2/aggs/t1/coefs
}

__global__ __launch_bounds__(256) void egnn_kernel(
    const float* __restrict__ xyz,  const float* __restrict__ feat,
    const float* __restrict__ we1,  const float* __restrict__ be1,
    const float* __restrict__ we2,  const float* __restrict__ be2,
    const float* __restrict__ wxw,  const float* __restrict__ bxw,
    const float* __restrict__ wh1,  const float* __restrict__ bh1,
    const float* __restrict__ wh2,  const float* __restrict__ bh2,
    const int* __restrict__ ws_idx, const int* __restrict__ ws_knn,
    float* __restrict__ out)
{
  __shared__ __align__(16) float hi[NC];
  __shared__ __align__(16) float hj[K2NN][NC];
  __shared__ float rel[K2NN][3];
  __shared__ float d2s[K2NN];
  __shared__ __align__(16) float s1[K2NN][S1STR];
  __shared__ __align__(16) float s2[K2NN][S1STR];
  __shared__ float coefs[K2NN];
  __shared__ float aggs[HH];
  __shared__ float t1[HH];
  __shared__ int   nidx[K2NN];

  const int blk = blockIdx.x;
  const int b = blk / MCENT, m = blk % MCENT;
  const int tid = threadIdx.x;
  const float* P = xyz + (size_t)b*NPTS*3;
  const float cx = out[OUT0_OFF + (size_t)(b*MCENT+m)*3 + 0];
  const float cy = out[OUT0_OFF + (size_t)(b*MCENT+m)*3 + 1];
  const float cz = out[OUT0_OFF + (size_t)(b*MCENT+m)*3 + 2];

  const int ci = ws_idx[b*MCENT + m];
  if (tid < NC)   hi[tid]   = feat[((size_t)b*NC + tid)*NPTS + ci];
  if (tid < K2NN) nidx[tid] = ws_knn[(size_t)blk*K2NN + tid];
  __syncthreads();

  if (tid < K2NN){
    const int p = nidx[tid];
    const float rx = cx - P[p*3+0];
    const float ry = cy - P[p*3+1];
    const float rz = cz - P[p*3+2];
    rel[tid][0]=rx; rel[tid][1]=ry; rel[tid][2]=rz;
    d2s[tid] = rx*rx + ry*ry + rz*rz;
  }
  {
    const int j  = tid >> 3;
    const int c0 = (tid & 7) * 8;
    const int p  = nidx[j];
    #pragma unroll
    for (int q = 0; q < 8; ++q)
      hj[j][c0+q] = feat[((size_t)b*NC + c0 + q)*NPTS + p];
  }
  __syncthreads();

  egnn_scale<16>(0, b, m, tid, we1, be1, we2, be2, wxw, bxw, wh1, bh1, wh2, bh2,
                 hi, hj, rel, d2s, s1, s2, coefs, aggs, t1, cx, cy, cz, out);
  egnn_scale<32>(1, b, m, tid, we1, be1, we2, be2, wxw, bxw, wh1, bh1, wh2, bh2,
                 hi, hj, rel, d2s, s1, s2, coefs, aggs, t1, cx, cy, cz, out);
}

// ---------------------------------------------------------------------------
extern "C" void kernel_launch(void* const* d_in, const int* in_sizes, int n_in,
                              void* d_out, int out_size, void* d_ws, size_t ws_size,
                              hipStream_t stream){
  const float* xyz = (const float*)d_in[0];
  const float* feat= (const float*)d_in[1];
  const float* we1 = (const float*)d_in[2];
  const float* be1 = (const float*)d_in[3];
  const float* we2 = (const float*)d_in[4];
  const float* be2 = (const float*)d_in[5];
  const float* wxw = (const float*)d_in[6];
  const float* bxw = (const float*)d_in[7];
  const float* wh1 = (const float*)d_in[8];
  const float* bh1 = (const float*)d_in[9];
  const float* wh2 = (const float*)d_in[10];
  const float* bh2 = (const float*)d_in[11];
  float* out = (float*)d_out;

  // workspace: idx (B*M int) + knn (B*M*32 int) = 528 KB
  int* ws_idx = (int*)d_ws;
  int* ws_knn = ws_idx + NB*MCENT;

  fps_kernel <<<dim3(NB),        dim3(512), 0, stream>>>(xyz, out, ws_idx);
  knn_kernel <<<dim3(NB*MCENT),  dim3(256), 0, stream>>>(xyz, out, ws_knn);
  egnn_kernel<<<dim3(NB*MCENT),  dim3(256), 0, stream>>>(xyz, feat,
      we1, be1, we2, be2, wxw, bxw, wh1, bh1, wh2, bh2, ws_idx, ws_knn, out);
}